// Round 17
// baseline (657.942 us; speedup 1.0000x reference)
//
#include <hip/hip_runtime.h>
#include <cstddef>
#include <cstdint>

constexpr int kN    = 1024;
constexpr int kE    = 8192;
constexpr int kQL   = 8;
constexpr int kHID  = 1024;

typedef __bf16 bf16x8 __attribute__((ext_vector_type(8)));
typedef float  f32x4  __attribute__((ext_vector_type(4)));
typedef unsigned short ushort8 __attribute__((ext_vector_type(8)));

__device__ __forceinline__ unsigned short f2bf(float f) {
  unsigned u = __float_as_uint(f);
  unsigned r = (u + 0x7FFFu + ((u >> 16) & 1u)) >> 16;
  return (unsigned short)r;
}
__device__ __forceinline__ float bf2f(unsigned short u) {
  return __uint_as_float((unsigned)u << 16);
}
__device__ __forceinline__ unsigned pkbf(float a, float b) {
  return (unsigned)f2bf(a) | ((unsigned)f2bf(b) << 16);
}
__device__ __forceinline__ void gload_lds16(const void* g, void* l) {
  __builtin_amdgcn_global_load_lds(
      (const __attribute__((address_space(1))) void*)g,
      (__attribute__((address_space(3))) void*)l, 16, 0, 0);
}
__device__ __forceinline__ void cvt8(const float* src, unsigned short* dst) {
  const float4* p = (const float4*)src;
  float4 a = p[0], b = p[1];
  uint4 o;
  o.x = f2bf(a.x) | ((unsigned)f2bf(a.y) << 16);
  o.y = f2bf(a.z) | ((unsigned)f2bf(a.w) << 16);
  o.z = f2bf(b.x) | ((unsigned)f2bf(b.y) << 16);
  o.w = f2bf(b.z) | ((unsigned)f2bf(b.w) << 16);
  *(uint4*)dst = o;
}

// ---------- merged pre-GEMM prep: rmsnorm1 + ALL cvts + rope + CSR ----------
// block segments (256 thr each):
//   [0,8192)            rmsnorm(hidden,ln1)->x16 (one block per row)
//   [8192,40960)        ehid -> eh16           (8,388,608 x8 chunks)
//   [40960,41472)       Wq   -> wqkv[0:]
//   [41472,41728)       Wk   -> wqkv[1024*1024:]
//   [41728,41984)       Wv   -> wqkv[1536*1024:]
//   [41984,42496)       Wo   -> wo16
//   [42496,44544)       Wdown-> wd16
//   [44544,48640)       gate/up interleave -> wgu16
//   48640               rope tables (512 entries, 2/thread)
//   48641               CSR build (histogram + scan + scatter, all in LDS)
__global__ __launch_bounds__(256) void prep_kernel(
    const float* __restrict__ hidden, const float* __restrict__ ln1,
    const float* __restrict__ ehid,
    const float* __restrict__ Wq, const float* __restrict__ Wk,
    const float* __restrict__ Wv, const float* __restrict__ Wo,
    const float* __restrict__ Wg, const float* __restrict__ Wu,
    const float* __restrict__ Wd,
    const int* __restrict__ dstIdx,
    unsigned short* __restrict__ x16, unsigned short* __restrict__ eh16,
    unsigned short* __restrict__ wqkv, unsigned short* __restrict__ wo16,
    unsigned short* __restrict__ wgu, unsigned short* __restrict__ wd16,
    float* __restrict__ ct, float* __restrict__ st,
    int* __restrict__ startb, int* __restrict__ elist) {
  __shared__ float red[4];
  __shared__ int lcnt[1024];
  __shared__ int lsum[256];
  __shared__ int lstart[1024];
  int b = blockIdx.x;
  const int tid = threadIdx.x;
  if (b < 8192) {                      // rmsnorm (verbatim r16 body)
    const float* p = hidden + (size_t)b * kHID + tid * 4;
    float4 v = *(const float4*)p;
    float ss = v.x*v.x + v.y*v.y + v.z*v.z + v.w*v.w;
    #pragma unroll
    for (int off = 32; off > 0; off >>= 1) ss += __shfl_down(ss, off);
    int lane = tid & 63, wv = tid >> 6;
    if (lane == 0) red[wv] = ss;
    __syncthreads();
    float tot = red[0] + red[1] + red[2] + red[3];
    float rn = rsqrtf(tot * (1.0f / (float)kHID) + 1e-6f);
    float4 w4 = *(const float4*)(ln1 + tid * 4);
    uint2 o;
    o.x = f2bf(v.x*rn*w4.x) | ((unsigned)f2bf(v.y*rn*w4.y) << 16);
    o.y = f2bf(v.z*rn*w4.z) | ((unsigned)f2bf(v.w*rn*w4.w) << 16);
    *(uint2*)(x16 + (size_t)b * kHID + tid * 4) = o;
    return;
  }
  b -= 8192;
  if (b < 32768) { size_t i = (size_t)b * 256 + tid; cvt8(ehid + i * 8, eh16 + i * 8); return; }
  b -= 32768;
  if (b < 512)  { size_t i = (size_t)b * 256 + tid; cvt8(Wq + i * 8, wqkv + i * 8); return; }
  b -= 512;
  if (b < 256)  { size_t i = (size_t)b * 256 + tid; cvt8(Wk + i * 8, wqkv + 1024 * 1024 + i * 8); return; }
  b -= 256;
  if (b < 256)  { size_t i = (size_t)b * 256 + tid; cvt8(Wv + i * 8, wqkv + 1536 * 1024 + i * 8); return; }
  b -= 256;
  if (b < 512)  { size_t i = (size_t)b * 256 + tid; cvt8(Wo + i * 8, wo16 + i * 8); return; }
  b -= 512;
  if (b < 2048) { size_t i = (size_t)b * 256 + tid; cvt8(Wd + i * 8, wd16 + i * 8); return; }
  b -= 2048;
  if (b < 4096) {                      // gate/up 16-col interleave (verbatim)
    int i = b * 256 + tid;             // < 1048576
    int n = i >> 7, ck = (i & 127) * 8;
    int isUp = (n >> 4) & 1;
    int srow = (n >> 6) * 32 + ((n >> 5) & 1) * 16 + (n & 15);
    const float* src = (isUp ? Wu : Wg) + (size_t)srow * 1024 + ck;
    cvt8(src, wgu + (size_t)n * 1024 + ck);
    return;
  }
  b -= 4096;
  if (b == 0) {                        // rope tables: 512 entries, 2/thread
    #pragma unroll
    for (int z = 0; z < 2; ++z) {
      int i = tid + z * 256;
      int p = i >> 5, j = i & 31;
      float inv = expf(-((float)(2 * j) / 64.0f) * logf(10000.0f));
      float ang = (float)p * inv;
      ct[i] = cosf(ang);
      st[i] = sinf(ang);
    }
    return;
  }
  // ---- CSR build (single block, all in LDS) ----
  for (int i = tid; i < 1024; i += 256) lcnt[i] = 0;
  __syncthreads();
  for (int e = tid; e < kE; e += 256) atomicAdd(&lcnt[dstIdx[e]], 1);
  __syncthreads();
  const int base = tid * 4;
  const int c0 = lcnt[base], c1 = lcnt[base + 1];
  const int c2 = lcnt[base + 2], c3 = lcnt[base + 3];
  const int tsum = c0 + c1 + c2 + c3;
  lsum[tid] = tsum;
  __syncthreads();
  for (int off = 1; off < 256; off <<= 1) {   // inclusive Hillis-Steele
    int add = (tid >= off) ? lsum[tid - off] : 0;
    __syncthreads();
    lsum[tid] += add;
    __syncthreads();
  }
  const int excl = lsum[tid] - tsum;          // exclusive prefix of this group
  lstart[base]     = excl;
  lstart[base + 1] = excl + c0;
  lstart[base + 2] = excl + c0 + c1;
  lstart[base + 3] = excl + c0 + c1 + c2;
  startb[base + 1] = excl + c0;
  startb[base + 2] = excl + c0 + c1;
  startb[base + 3] = excl + c0 + c1 + c2;
  startb[base + 4] = excl + tsum;
  if (tid == 0) startb[0] = 0;
  __syncthreads();
  for (int i = tid; i < 1024; i += 256) lcnt[i] = 0;   // reuse as cursor
  __syncthreads();
  for (int e = tid; e < kE; e += 256) {
    int d = dstIdx[e];
    int pos = atomicAdd(&lcnt[d], 1);
    elist[lstart[d] + pos] = e;
  }
}

// ---------- RMSNorm: bf16 in -> bf16 out (for h in bf16) ----------
__global__ __launch_bounds__(256) void rmsnorm_b16in_kernel(
    const unsigned short* __restrict__ in, const float* __restrict__ w,
    unsigned short* __restrict__ out) {
  __shared__ float red[4];
  int row = blockIdx.x, tid = threadIdx.x;
  uint2 u = *(const uint2*)(in + (size_t)row * kHID + tid * 4);
  float v0 = bf2f((unsigned short)(u.x & 0xffff));
  float v1 = bf2f((unsigned short)(u.x >> 16));
  float v2 = bf2f((unsigned short)(u.y & 0xffff));
  float v3 = bf2f((unsigned short)(u.y >> 16));
  float ss = v0*v0 + v1*v1 + v2*v2 + v3*v3;
  #pragma unroll
  for (int off = 32; off > 0; off >>= 1) ss += __shfl_down(ss, off);
  int lane = tid & 63, wv = tid >> 6;
  if (lane == 0) red[wv] = ss;
  __syncthreads();
  float tot = red[0] + red[1] + red[2] + red[3];
  float rn = rsqrtf(tot * (1.0f / (float)kHID) + 1e-6f);
  float4 w4 = *(const float4*)(w + tid * 4);
  uint2 o;
  o.x = f2bf(v0*rn*w4.x) | ((unsigned)f2bf(v1*rn*w4.y) << 16);
  o.y = f2bf(v2*rn*w4.z) | ((unsigned)f2bf(v3*rn*w4.w) << 16);
  *(uint2*)(out + (size_t)row * kHID + tid * 4) = o;
}

// ---------- 256x256 8-phase bf16 MFMA GEMM (r16 VERBATIM) ----------
// OUTMODE: 2=silu(gate)*up pairs->bf16 (N_out=N/2)
//          3=bf16 + k-rope cols [0,512) posOdd   4=bf16 + q-rope [0,1024),
//            k-rope [1024,1536) pos even
template<int OUTMODE>
__global__ __launch_bounds__(512, 2) void gemm8p(
    const unsigned short* __restrict__ A, const unsigned short* __restrict__ B,
    const float* __restrict__ resid, void* __restrict__ Cout,
    const float* __restrict__ ct, const float* __restrict__ st,
    int M, int N, int K) {
  __shared__ unsigned short As[2][2][128][64];   // [buf][half][row][col] 64 KiB
  __shared__ unsigned short Bs[2][2][128][64];   // 64 KiB
  const int tid = threadIdx.x;
  const int lane = tid & 63, wid = tid >> 6;
  const int gx = gridDim.x;
  int id = blockIdx.y * gx + blockIdx.x;
  {
    const int nwg = gx * gridDim.y;           // all grids here are %8 == 0
    const int cpx = nwg >> 3;
    id = (id & 7) * cpx + (id >> 3);          // XCD-contiguous remap
  }
  const int m0 = (id / gx) * 256, n0 = (id % gx) * 256;
  const int wr = wid >> 2, wc = wid & 3;
  const int l15 = lane & 15, lg = lane >> 4;
  const int swz = l15 & 7;
  const int NT = K >> 6;                      // BK=64 tiles (always even here)

  const int scol = ((lane & 7) ^ (lane >> 3)) * 8;
  const unsigned short* Asrc = A + (size_t)(m0 + wid * 16 + (lane >> 3)) * K + scol;
  const unsigned short* Bsrc = B + (size_t)(n0 + wid * 16 + (lane >> 3)) * K + scol;
  const size_t rK8 = (size_t)8 * K, rK128 = (size_t)128 * K;
  const int brow0 = (wc & 1) * 64;            // wave's B rows within half wc>>1

#define STAGEA(t_, h_, b_) do {                                              \
    gload_lds16(Asrc + (size_t)(h_) * rK128 + (size_t)(t_) * 64,             \
                (unsigned short*)&As[b_][h_][0][0] + (wid * 2 + 0) * 512);   \
    gload_lds16(Asrc + (size_t)(h_) * rK128 + rK8 + (size_t)(t_) * 64,       \
                (unsigned short*)&As[b_][h_][0][0] + (wid * 2 + 1) * 512);   \
  } while (0)
#define STAGEB(t_, h_, b_) do {                                              \
    gload_lds16(Bsrc + (size_t)(h_) * rK128 + (size_t)(t_) * 64,             \
                (unsigned short*)&Bs[b_][h_][0][0] + (wid * 2 + 0) * 512);   \
    gload_lds16(Bsrc + (size_t)(h_) * rK128 + rK8 + (size_t)(t_) * 64,       \
                (unsigned short*)&Bs[b_][h_][0][0] + (wid * 2 + 1) * 512);   \
  } while (0)

  bf16x8 afr[2][4], bfr[2][4];   // [kk][mi'] / [kk][nj] — constant-indexed only
#define LOADA(b_, qm_) do {                                                  \
    _Pragma("unroll") for (int kk = 0; kk < 2; ++kk)                         \
    _Pragma("unroll") for (int mi = 0; mi < 4; ++mi)                         \
      afr[kk][mi] = *(const bf16x8*)&As[b_][wr][((qm_) * 4 + mi) * 16 + l15] \
                                       [((kk * 4 + lg) ^ swz) * 8];          \
  } while (0)
#define LOADB(b_, qn_) do {                                                  \
    _Pragma("unroll") for (int kk = 0; kk < 2; ++kk)                         \
    _Pragma("unroll") for (int nj = 0; nj < 2; ++nj)                         \
      bfr[kk][(qn_) * 2 + nj] =                                              \
        *(const bf16x8*)&Bs[b_][wc >> 1][brow0 + ((qn_) * 2 + nj) * 16 + l15]\
                           [((kk * 4 + lg) ^ swz) * 8];                      \
  } while (0)

  f32x4 acc[8][4] = {};
#define MFMAQ(qm_, qn_) do {                                                 \
    __builtin_amdgcn_s_setprio(1);                                           \
    _Pragma("unroll") for (int mi = 0; mi < 4; ++mi)                         \
    _Pragma("unroll") for (int nj = 0; nj < 2; ++nj) {                       \
      acc[(qm_) * 4 + mi][(qn_) * 2 + nj] =                                  \
        __builtin_amdgcn_mfma_f32_16x16x32_bf16(afr[0][mi],                  \
          bfr[0][(qn_) * 2 + nj], acc[(qm_) * 4 + mi][(qn_) * 2 + nj], 0,0,0);\
      acc[(qm_) * 4 + mi][(qn_) * 2 + nj] =                                  \
        __builtin_amdgcn_mfma_f32_16x16x32_bf16(afr[1][mi],                  \
          bfr[1][(qn_) * 2 + nj], acc[(qm_) * 4 + mi][(qn_) * 2 + nj], 0,0,0);\
    }                                                                        \
    __builtin_amdgcn_s_setprio(0);                                           \
  } while (0)

#define BAR_PRE() do {                                                       \
    __builtin_amdgcn_sched_barrier(0);                                       \
    __builtin_amdgcn_s_barrier();                                            \
    asm volatile("s_waitcnt lgkmcnt(0)" ::: "memory");                       \
    __builtin_amdgcn_sched_barrier(0);                                       \
  } while (0)
#define BAR_POST() do {                                                      \
    __builtin_amdgcn_sched_barrier(0);                                       \
    __builtin_amdgcn_s_barrier();                                            \
    __builtin_amdgcn_sched_barrier(0);                                       \
  } while (0)

  // prologue: T0 fully + T1.B; drain T0 (leave T1.B in flight)
  STAGEA(0, 0, 0); STAGEA(0, 1, 0); STAGEB(0, 0, 0); STAGEB(0, 1, 0);
  STAGEB(1, 0, 1); STAGEB(1, 1, 1);
  asm volatile("s_waitcnt vmcnt(4)" ::: "memory");
  __builtin_amdgcn_sched_barrier(0);
  __builtin_amdgcn_s_barrier();
  __builtin_amdgcn_sched_barrier(0);

  for (int t0 = 0; t0 < NT; t0 += 2) {
    const bool more = (t0 + 2 < NT);   // next tile-pair exists (t0+2 and t0+3)
    // ---- tile t0 (buf 0) ----
    LOADA(0, 0); LOADB(0, 0);                 // ph1: A-lo + B01
    STAGEA(t0 + 1, 0, 1);
    BAR_PRE(); MFMAQ(0, 0); BAR_POST();
    LOADB(0, 1);                              // ph2: B23
    STAGEA(t0 + 1, 1, 1);
    BAR_PRE(); MFMAQ(0, 1); BAR_POST();
    LOADA(0, 1);                              // ph3: A-hi
    if (more) STAGEB(t0 + 2, 0, 0);
    BAR_PRE(); MFMAQ(1, 0); BAR_POST();
    if (more) STAGEB(t0 + 2, 1, 0);           // ph4 (late vmcnt)
    BAR_PRE(); MFMAQ(1, 1);
    __builtin_amdgcn_sched_barrier(0);
    if (more) asm volatile("s_waitcnt vmcnt(4)" ::: "memory");
    else      asm volatile("s_waitcnt vmcnt(0)" ::: "memory");
    BAR_POST();
    // ---- tile t0+1 (buf 1) ----
    LOADA(1, 0); LOADB(1, 0);                 // ph5
    if (more) STAGEA(t0 + 2, 0, 0);
    BAR_PRE(); MFMAQ(0, 0); BAR_POST();
    LOADB(1, 1);                              // ph6
    if (more) STAGEA(t0 + 2, 1, 0);
    BAR_PRE(); MFMAQ(0, 1); BAR_POST();
    LOADA(1, 1);                              // ph7
    if (more) STAGEB(t0 + 3, 0, 1);
    BAR_PRE(); MFMAQ(1, 0); BAR_POST();
    if (more) STAGEB(t0 + 3, 1, 1);           // ph8 (late vmcnt)
    BAR_PRE(); MFMAQ(1, 1);
    __builtin_amdgcn_sched_barrier(0);
    if (more) asm volatile("s_waitcnt vmcnt(4)" ::: "memory");
    BAR_POST();
  }
#undef STAGEA
#undef STAGEB
#undef LOADA
#undef LOADB
#undef MFMAQ
#undef BAR_PRE
#undef BAR_POST

  // ---------- epilogue ----------
  const int r0 = lg * 4;
  const int bc = n0 + wc * 64;
  #pragma unroll
  for (int mi = 0; mi < 8; ++mi) {
    #pragma unroll
    for (int r = 0; r < 4; ++r) {
      const size_t grow = (size_t)(m0 + wr * 128 + mi * 16 + r0 + r);
      if (OUTMODE == 2) {
        #pragma unroll
        for (int p = 0; p < 2; ++p) {
          float gv = acc[mi][2 * p][r], uv = acc[mi][2 * p + 1][r];
          float res = gv / (1.f + __expf(-gv)) * uv;
          ((unsigned short*)Cout)[grow * (size_t)(N >> 1) + (bc >> 1) + p * 16 + l15] = f2bf(res);
        }
      } else {
        bool doR = false; int pos = 0;
        if (OUTMODE == 3) { doR = bc < 512; pos = 2 * ((int)grow & 7) + 1; }
        if (OUTMODE == 4) {
          if (bc < 1024)      { doR = true; pos = (int)grow & 7; }
          else if (bc < 1536) { doR = true; pos = 2 * ((int)grow & 7); }
        }
        unsigned short* o16 = (unsigned short*)Cout;
        if (doR) {
          #pragma unroll
          for (int nj = 0; nj < 2; ++nj) {
            float a = acc[mi][nj][r], b = acc[mi][nj + 2][r];
            float c = ct[pos * 32 + nj * 16 + l15];
            float s = st[pos * 32 + nj * 16 + l15];
            o16[grow * N + bc + nj * 16 + l15]       = f2bf(a * c - b * s);
            o16[grow * N + bc + (nj + 2) * 16 + l15] = f2bf(b * c + a * s);
          }
        } else {
          #pragma unroll
          for (int nj = 0; nj < 4; ++nj)
            o16[grow * N + bc + nj * 16 + l15] = f2bf(acc[mi][nj][r]);
        }
      }
    }
  }
}

// ---------- TMx128 bf16 MFMA GEMM, BK=32, 3-buffer LDS (r16 VERBATIM) ----------
// OUTMODE: 5 = bf16 out + f32 resid (Wo -> hbuf16)
//          6 = f32 out + bf16 resid (Down -> d_out, resid=hbuf16)
template<int OUTMODE, int TM>
__global__ __launch_bounds__(512, 4) void gemmk(
    const unsigned short* __restrict__ A, const unsigned short* __restrict__ B,
    const void* __restrict__ residv, void* __restrict__ Cout,
    const float* __restrict__ ct, const float* __restrict__ st,
    int M, int N, int K) {
  constexpr int ABUFE = TM * 32;            // elems per A buffer
  constexpr int BBUFE = 128 * 32;
  constexpr int WRS   = TM / 4;             // wave row span: 64 or 32
  constexpr int MI    = WRS / 16;           // 4 or 2
  constexpr int LPS   = (TM == 256) ? 3 : 2; // gloads per stage per wave
  __shared__ unsigned short As[3 * ABUFE];
  __shared__ unsigned short Bs[3 * BBUFE];
  const int tid = threadIdx.x;
  const int lane = tid & 63, wid = tid >> 6;
  const int gx = gridDim.x;
  int id = blockIdx.y * gx + blockIdx.x;
  {
    const int nwg = gx * gridDim.y;         // all grids here are %8 == 0
    const int cpx = nwg >> 3;
    id = (id & 7) * cpx + (id >> 3);        // XCD-contiguous remap
  }
  const int m0 = (id / gx) * TM, n0 = (id % gx) * 128;
  const int wr = wid >> 1, wc = wid & 1;
  const int l15 = lane & 15, lg = lane >> 4;
  const int NT = K >> 5;

  const int sr4 = lane >> 2, sc = lane & 3;
  const int arow0 = (TM == 256) ? (wid * 32 + sr4) : (wid * 16 + sr4);
  const int brow0 = wid * 16 + sr4;
  const unsigned short* Asrc = A + (size_t)(m0 + arow0) * K + (sc ^ ((arow0 >> 1) & 3)) * 8;
  const unsigned short* Bsrc = B + (size_t)(n0 + brow0) * K + (sc ^ ((brow0 >> 1) & 3)) * 8;
  const size_t rK16 = (size_t)16 * K;

#define STAGE(t_, b_) do {                                                   \
    const size_t _k0 = (size_t)(t_) * 32;                                    \
    if (TM == 256) {                                                         \
      gload_lds16(Asrc + _k0,        As + (b_) * ABUFE + wid * 1024);        \
      gload_lds16(Asrc + rK16 + _k0, As + (b_) * ABUFE + wid * 1024 + 512);  \
    } else {                                                                 \
      gload_lds16(Asrc + _k0,        As + (b_) * ABUFE + wid * 512);         \
    }                                                                        \
    gload_lds16(Bsrc + _k0,          Bs + (b_) * BBUFE + wid * 512);         \
  } while (0)

  f32x4 acc[MI][4] = {};
  STAGE(0, 0); STAGE(1, 1);

  const int rck = (lg ^ ((l15 >> 1) & 3)) * 8;   // read-side swizzle chunk
  int cur = 0, nx2 = 2;
  for (int t = 0; t < NT; ++t) {
    __builtin_amdgcn_sched_barrier(0);
    if (t + 1 < NT) asm volatile("s_waitcnt vmcnt(%0)" :: "i"(LPS) : "memory");
    else            asm volatile("s_waitcnt vmcnt(0)" ::: "memory");
    __builtin_amdgcn_s_barrier();
    __builtin_amdgcn_sched_barrier(0);
    if (t + 2 < NT) STAGE(t + 2, nx2);

    const unsigned short* Ab = As + cur * ABUFE + (wr * WRS + l15) * 32 + rck;
    const unsigned short* Bb = Bs + cur * BBUFE + (wc * 64 + l15) * 32 + rck;
    bf16x8 af[MI], bf[4];
    #pragma unroll
    for (int mi = 0; mi < MI; ++mi) af[mi] = *(const bf16x8*)(Ab + mi * 512);
    #pragma unroll
    for (int nj = 0; nj < 4; ++nj) bf[nj] = *(const bf16x8*)(Bb + nj * 512);
    __builtin_amdgcn_s_setprio(1);
    #pragma unroll
    for (int mi = 0; mi < MI; ++mi)
      #pragma unroll
      for (int nj = 0; nj < 4; ++nj)
        acc[mi][nj] = __builtin_amdgcn_mfma_f32_16x16x32_bf16(af[mi], bf[nj], acc[mi][nj], 0, 0, 0);
    __builtin_amdgcn_s_setprio(0);
    cur = (cur == 2) ? 0 : cur + 1;
    nx2 = (nx2 == 2) ? 0 : nx2 + 1;
  }
#undef STAGE

  const int r0 = lg * 4;
  const int bc = n0 + wc * 64;
  #pragma unroll
  for (int mi = 0; mi < MI; ++mi) {
    #pragma unroll
    for (int r = 0; r < 4; ++r) {
      const size_t grow = (size_t)(m0 + wr * WRS + mi * 16 + r0 + r);
      #pragma unroll
      for (int nj = 0; nj < 4; ++nj) {
        const size_t gi = grow * N + (bc + nj * 16 + l15);
        float v = acc[mi][nj][r];
        if (OUTMODE == 5) {
          v += ((const float*)residv)[gi];
          ((unsigned short*)Cout)[gi] = f2bf(v);
        } else {  // OUTMODE 6
          v += bf2f(((const unsigned short*)residv)[gi]);
          ((float*)Cout)[gi] = v;
        }
      }
    }
  }
}

// ---------- MFMA graph attention: one wave per (node, kv-head) (r16 VERBATIM) ----------
__global__ __launch_bounds__(256) void attn_mfma_kernel(
    const unsigned short* __restrict__ qkv,  // roped
    const unsigned short* __restrict__ ekv,  // ek roped
    const int* __restrict__ srcIdx, const int* __restrict__ elist,
    const int* __restrict__ start,
    unsigned short* __restrict__ aggb) {
  const int n = blockIdx.x >> 1;
  const int g = (blockIdx.x & 1) * 4 + (threadIdx.x >> 6);
  const int lane = threadIdx.x & 63;
  const int l15 = lane & 15, lg = lane >> 4;

  const int h = g * 2 + (l15 >> 3), q = l15 & 7;
  const unsigned short* qrow = qkv + ((size_t)n * 8 + q) * 2048 + h * 64 + lg * 8;
  const bf16x8 qf0 = *(const bf16x8*)qrow;
  const bf16x8 qf1 = *(const bf16x8*)(qrow + 32);

  float m = -3.4e38f, sh = 0.f;
  f32x4 oacc[4];
  #pragma unroll
  for (int t = 0; t < 4; ++t) oacc[t] = (f32x4){0.f, 0.f, 0.f, 0.f};

  const int kparity = l15 & 1;
  const int t_ = l15 >> 1;
  const int lgh = lg & 1;
  const int eS = lg >> 1;

  const int s0 = start[n], s1 = start[n + 1];
  for (int jj = s0; jj < s1; jj += 2) {
    const int e0 = elist[jj];
    const bool has1 = (jj + 1 < s1);
    const int e1 = has1 ? elist[jj + 1] : e0;
    const int sn0 = srcIdx[e0], sn1 = srcIdx[e1];

    const unsigned short* kr0 = kparity
        ? ekv + ((size_t)e0 * 8 + t_) * 1024 + g * 64 + lg * 8
        : qkv + ((size_t)sn0 * 8 + t_) * 2048 + 1024 + g * 64 + lg * 8;
    const unsigned short* kr1 = kparity
        ? ekv + ((size_t)e1 * 8 + t_) * 1024 + g * 64 + lg * 8
        : qkv + ((size_t)sn1 * 8 + t_) * 2048 + 1024 + g * 64 + lg * 8;
    bf16x8 ka0 = *(const bf16x8*)kr0, ka1 = *(const bf16x8*)(kr0 + 32);
    bf16x8 kc0 = *(const bf16x8*)kr1, kc1 = *(const bf16x8*)(kr1 + 32);

    const int evsel = eS ? e1 : e0;
    const int snsel = eS ? sn1 : sn0;
    const unsigned short* vn = qkv + ((size_t)snsel * 8 + lgh * 4) * 2048 + 1536 + g * 64;
    const unsigned short* ve = ekv + ((size_t)evsel * 8 + lgh * 4) * 1024 + 512 + g * 64;

    f32x4 z = (f32x4){0.f, 0.f, 0.f, 0.f};
    f32x4 sa = __builtin_amdgcn_mfma_f32_16x16x32_bf16(ka0, qf0, z, 0, 0, 0);
    sa       = __builtin_amdgcn_mfma_f32_16x16x32_bf16(ka1, qf1, sa, 0, 0, 0);
    f32x4 sb = __builtin_amdgcn_mfma_f32_16x16x32_bf16(kc0, qf0, z, 0, 0, 0);
    sb       = __builtin_amdgcn_mfma_f32_16x16x32_bf16(kc1, qf1, sb, 0, 0, 0);

    float l0[4], l1[4];
    float lmax = -3.4e38f;
    #pragma unroll
    for (int r = 0; r < 4; ++r) {
      l0[r] = sa[r] * 0.125f;
      l1[r] = has1 ? sb[r] * 0.125f : -3.4e38f;
      lmax = fmaxf(lmax, fmaxf(l0[r], l1[r]));
    }
    lmax = fmaxf(lmax, __shfl_xor(lmax, 16));
    lmax = fmaxf(lmax, __shfl_xor(lmax, 32));
    const float mnew = fmaxf(m, lmax);
    const float scale = __expf(m - mnew);
    float p0[4], p1[4], ps = 0.f;
    #pragma unroll
    for (int r = 0; r < 4; ++r) {
      p0[r] = __expf(l0[r] - mnew);
      p1[r] = __expf(l1[r] - mnew);
      ps += p0[r] + p1[r];
    }
    ps += __shfl_xor(ps, 16);
    ps += __shfl_xor(ps, 32);
    sh = sh * scale + ps;
    m = mnew;

    #pragma unroll
    for (int r = 0; r < 4; ++r) {
      float sr = __shfl(scale, lg * 4 + r);
      #pragma unroll
      for (int t = 0; t < 4; ++t) oacc[t][r] *= sr;
    }

    unsigned w00 = pkbf(p0[0], p0[1]), w01 = pkbf(p0[2], p0[3]);
    unsigned w10 = pkbf(p1[0], p1[1]), w11 = pkbf(p1[2], p1[3]);
    const int L1 = l15 + 32 * lgh, L2 = L1 + 16;
    unsigned a0 = __shfl(w00, L1), a1 = __shfl(w01, L1);
    unsigned a2 = __shfl(w00, L2), a3 = __shfl(w01, L2);
    unsigned b0 = __shfl(w10, L1), b1 = __shfl(w11, L1);
    unsigned b2 = __shfl(w10, L2), b3 = __shfl(w11, L2);
    uint4 wv;
    wv.x = eS ? b0 : a0; wv.y = eS ? b1 : a1;
    wv.z = eS ? b2 : a2; wv.w = eS ? b3 : a3;
    const bf16x8 pf = __builtin_bit_cast(bf16x8, wv);

    #pragma unroll
    for (int t = 0; t < 4; ++t) {
      const int col = t * 16 + l15;
      ushort8 vr;
      #pragma unroll
      for (int j = 0; j < 8; ++j)
        vr[j] = (j & 1) ? ve[(j >> 1) * 1024 + col] : vn[(j >> 1) * 2048 + col];
      const bf16x8 vf = __builtin_bit_cast(bf16x8, vr);
      oacc[t] = __builtin_amdgcn_mfma_f32_16x16x32_bf16(pf, vf, oacc[t], 0, 0, 0);
    }
  }

  #pragma unroll
  for (int r = 0; r < 4; ++r) {
    const float sr = __shfl(sh, lg * 4 + r);
    const float inv = 1.f / (sr + 1e-16f);
    const int hq = lg * 4 + r;
    const int hh = g * 2 + (hq >> 3), qq = hq & 7;
    unsigned short* op = aggb + ((size_t)n * 8 + qq) * 1024 + hh * 64 + l15;
    #pragma unroll
    for (int t = 0; t < 4; ++t) op[t * 16] = f2bf(oacc[t][r] * inv);
  }
}

extern "C" void kernel_launch(void* const* d_in, const int* in_sizes, int n_in,
                              void* d_out, int out_size, void* d_ws, size_t ws_size,
                              hipStream_t stream) {
  const float* hidden = (const float*)d_in[0];
  const int*   eidx   = (const int*)d_in[1];
  const float* ehid   = (const float*)d_in[2];
  const float* Wq     = (const float*)d_in[3];
  const float* Wk     = (const float*)d_in[4];
  const float* Wv     = (const float*)d_in[5];
  const float* Wo     = (const float*)d_in[6];
  const float* Wgate  = (const float*)d_in[7];
  const float* Wup    = (const float*)d_in[8];
  const float* Wdown  = (const float*)d_in[9];
  const float* ln1    = (const float*)d_in[10];
  const float* ln2    = (const float*)d_in[11];
  const int* srcIdx = eidx;
  const int* dstIdx = eidx + kE;

  char* wsb = (char*)d_ws;
  size_t off = 0;
  auto alloc = [&](size_t bytes) { char* p = wsb + off; off += (bytes + 255) & ~(size_t)255; return p; };
  unsigned short* eh16   = (unsigned short*)alloc(134217728);  // [65536][1024]
  unsigned short* ekv16  = (unsigned short*)alloc(134217728);  // [65536][1024] ek|ev; reused as gm16 [8192][4096]
  unsigned short* qkv16  = (unsigned short*)alloc(33554432);   // [8192][2048] q|k|v
  unsigned short* x16    = (unsigned short*)alloc(16777216);   // [8192][1024]; reused as h216
  unsigned short* agg16  = (unsigned short*)alloc(16777216);   // [8192][1024]
  unsigned short* hbuf16 = (unsigned short*)alloc(16777216);   // [8192][1024] bf16 (h)
  unsigned short* wqkv16 = (unsigned short*)alloc(4194304);    // [2048][1024] = Wq|Wk|Wv
  unsigned short* wo16   = (unsigned short*)alloc(2097152);    // [1024][1024]
  unsigned short* wgu16  = (unsigned short*)alloc(16777216);   // [8192][1024] interleaved gate/up
  unsigned short* wd16   = (unsigned short*)alloc(8388608);    // [1024][4096]
  int* startb = (int*)alloc(4352);   // 1025 ints
  int* elist  = (int*)alloc(32768);
  float* ct   = (float*)alloc(2048);
  float* st   = (float*)alloc(2048);
  unsigned short* gm16 = ekv16;   // silu output (ekv dead after attention)
  unsigned short* h216 = x16;     // rmsnorm2 out (x16 dead after QKV GEMM)
  float* outp = (float*)d_out;

  // merged prep: rmsnorm1 + all conversions + rope tables + CSR (1 launch)
  prep_kernel<<<48642, 256, 0, stream>>>(hidden, ln1, ehid,
                                         Wq, Wk, Wv, Wo, Wgate, Wup, Wdown,
                                         dstIdx,
                                         x16, eh16, wqkv16, wo16, wgu16, wd16,
                                         ct, st, startb, elist);

  // fused projections (rope fused in epilogues) — 8-phase for the big GEMMs
  gemm8p<4><<<dim3(8, 32),  512, 0, stream>>>(x16,  wqkv16, nullptr, qkv16, ct, st, 8192, 2048, 1024);
  gemm8p<3><<<dim3(4, 256), 512, 0, stream>>>(eh16, wqkv16 + 1024 * 1024, nullptr, ekv16, ct, st, 65536, 1024, 1024);

  // fused MFMA graph attention
  attn_mfma_kernel<<<2048, 256, 0, stream>>>(qkv16, ekv16, srcIdx, elist, startb, agg16);

  // h = hidden + agg @ Wo^T  -> bf16 hbuf
  gemmk<5, 128><<<dim3(8, 64), 512, 0, stream>>>(agg16, wo16, hidden, hbuf16, ct, st, 8192, 1024, 1024);

  // MLP (silu fused in GateUp epilogue via interleaved weights)
  rmsnorm_b16in_kernel<<<kN * kQL, 256, 0, stream>>>(hbuf16, ln2, h216);
  gemm8p<2><<<dim3(32, 32), 512, 0, stream>>>(h216, wgu16, nullptr, gm16, ct, st, 8192, 8192, 1024);
  gemmk<6, 128><<<dim3(8, 64), 512, 0, stream>>>(gm16, wd16, hbuf16, outp, ct, st, 8192, 1024, 4096);
}

// Round 18
// 650.170 us; speedup vs baseline: 1.0120x; 1.0120x over previous
//
#include <hip/hip_runtime.h>
#include <cstddef>
#include <cstdint>

constexpr int kN    = 1024;
constexpr int kE    = 8192;
constexpr int kQL   = 8;
constexpr int kHID  = 1024;

typedef __bf16 bf16x8 __attribute__((ext_vector_type(8)));
typedef float  f32x4  __attribute__((ext_vector_type(4)));
typedef unsigned short ushort8 __attribute__((ext_vector_type(8)));

__device__ __forceinline__ unsigned short f2bf(float f) {
  unsigned u = __float_as_uint(f);
  unsigned r = (u + 0x7FFFu + ((u >> 16) & 1u)) >> 16;
  return (unsigned short)r;
}
__device__ __forceinline__ float bf2f(unsigned short u) {
  return __uint_as_float((unsigned)u << 16);
}
__device__ __forceinline__ unsigned pkbf(float a, float b) {
  return (unsigned)f2bf(a) | ((unsigned)f2bf(b) << 16);
}
__device__ __forceinline__ void gload_lds16(const void* g, void* l) {
  __builtin_amdgcn_global_load_lds(
      (const __attribute__((address_space(1))) void*)g,
      (__attribute__((address_space(3))) void*)l, 16, 0, 0);
}
__device__ __forceinline__ void cvt8(const float* src, unsigned short* dst) {
  const float4* p = (const float4*)src;
  float4 a = p[0], b = p[1];
  uint4 o;
  o.x = f2bf(a.x) | ((unsigned)f2bf(a.y) << 16);
  o.y = f2bf(a.z) | ((unsigned)f2bf(a.w) << 16);
  o.z = f2bf(b.x) | ((unsigned)f2bf(b.y) << 16);
  o.w = f2bf(b.z) | ((unsigned)f2bf(b.w) << 16);
  *(uint4*)dst = o;
}

// ---------- merged pre-GEMM prep: rmsnorm1 + ALL fp32->bf16 cvts + rope ----------
// block segments (256 thr each):
//   [0,8192)            rmsnorm(hidden,ln1)->x16 (one block per row)
//   [8192,40960)        ehid -> eh16           (8,388,608 x8 chunks)
//   [40960,41472)       Wq   -> wqkv[0:]       (131072 chunks)
//   [41472,41728)       Wk   -> wqkv[1024*1024:]
//   [41728,41984)       Wv   -> wqkv[1536*1024:]
//   [41984,42496)       Wo   -> wo16
//   [42496,44544)       Wdown-> wd16           (524288 chunks)
//   [44544,48640)       gate/up interleave -> wgu16 (1,048,576 items)
//   48640               rope tables (512 entries, 2/thread)
__global__ __launch_bounds__(256) void prep_kernel(
    const float* __restrict__ hidden, const float* __restrict__ ln1,
    const float* __restrict__ ehid,
    const float* __restrict__ Wq, const float* __restrict__ Wk,
    const float* __restrict__ Wv, const float* __restrict__ Wo,
    const float* __restrict__ Wg, const float* __restrict__ Wu,
    const float* __restrict__ Wd,
    unsigned short* __restrict__ x16, unsigned short* __restrict__ eh16,
    unsigned short* __restrict__ wqkv, unsigned short* __restrict__ wo16,
    unsigned short* __restrict__ wgu, unsigned short* __restrict__ wd16,
    float* __restrict__ ct, float* __restrict__ st) {
  int b = blockIdx.x;
  const int tid = threadIdx.x;
  if (b < 8192) {                      // rmsnorm (verbatim r15 body)
    __shared__ float red[4];
    const float* p = hidden + (size_t)b * kHID + tid * 4;
    float4 v = *(const float4*)p;
    float ss = v.x*v.x + v.y*v.y + v.z*v.z + v.w*v.w;
    #pragma unroll
    for (int off = 32; off > 0; off >>= 1) ss += __shfl_down(ss, off);
    int lane = tid & 63, wv = tid >> 6;
    if (lane == 0) red[wv] = ss;
    __syncthreads();
    float tot = red[0] + red[1] + red[2] + red[3];
    float rn = rsqrtf(tot * (1.0f / (float)kHID) + 1e-6f);
    float4 w4 = *(const float4*)(ln1 + tid * 4);
    uint2 o;
    o.x = f2bf(v.x*rn*w4.x) | ((unsigned)f2bf(v.y*rn*w4.y) << 16);
    o.y = f2bf(v.z*rn*w4.z) | ((unsigned)f2bf(v.w*rn*w4.w) << 16);
    *(uint2*)(x16 + (size_t)b * kHID + tid * 4) = o;
    return;
  }
  b -= 8192;
  if (b < 32768) { size_t i = (size_t)b * 256 + tid; cvt8(ehid + i * 8, eh16 + i * 8); return; }
  b -= 32768;
  if (b < 512)  { size_t i = (size_t)b * 256 + tid; cvt8(Wq + i * 8, wqkv + i * 8); return; }
  b -= 512;
  if (b < 256)  { size_t i = (size_t)b * 256 + tid; cvt8(Wk + i * 8, wqkv + 1024 * 1024 + i * 8); return; }
  b -= 256;
  if (b < 256)  { size_t i = (size_t)b * 256 + tid; cvt8(Wv + i * 8, wqkv + 1536 * 1024 + i * 8); return; }
  b -= 256;
  if (b < 512)  { size_t i = (size_t)b * 256 + tid; cvt8(Wo + i * 8, wo16 + i * 8); return; }
  b -= 512;
  if (b < 2048) { size_t i = (size_t)b * 256 + tid; cvt8(Wd + i * 8, wd16 + i * 8); return; }
  b -= 2048;
  if (b < 4096) {                      // gate/up 16-col interleave (verbatim)
    int i = b * 256 + tid;             // < 1048576
    int n = i >> 7, ck = (i & 127) * 8;
    int isUp = (n >> 4) & 1;
    int srow = (n >> 6) * 32 + ((n >> 5) & 1) * 16 + (n & 15);
    const float* src = (isUp ? Wu : Wg) + (size_t)srow * 1024 + ck;
    cvt8(src, wgu + (size_t)n * 1024 + ck);
    return;
  }
  // rope tables: 512 entries, 2 per thread
  #pragma unroll
  for (int z = 0; z < 2; ++z) {
    int i = tid + z * 256;
    int p = i >> 5, j = i & 31;
    float inv = expf(-((float)(2 * j) / 64.0f) * logf(10000.0f));
    float ang = (float)p * inv;
    ct[i] = cosf(ang);
    st[i] = sinf(ang);
  }
}

// ---------- RMSNorm: bf16 in -> bf16 out (for h in bf16) ----------
__global__ __launch_bounds__(256) void rmsnorm_b16in_kernel(
    const unsigned short* __restrict__ in, const float* __restrict__ w,
    unsigned short* __restrict__ out) {
  __shared__ float red[4];
  int row = blockIdx.x, tid = threadIdx.x;
  uint2 u = *(const uint2*)(in + (size_t)row * kHID + tid * 4);
  float v0 = bf2f((unsigned short)(u.x & 0xffff));
  float v1 = bf2f((unsigned short)(u.x >> 16));
  float v2 = bf2f((unsigned short)(u.y & 0xffff));
  float v3 = bf2f((unsigned short)(u.y >> 16));
  float ss = v0*v0 + v1*v1 + v2*v2 + v3*v3;
  #pragma unroll
  for (int off = 32; off > 0; off >>= 1) ss += __shfl_down(ss, off);
  int lane = tid & 63, wv = tid >> 6;
  if (lane == 0) red[wv] = ss;
  __syncthreads();
  float tot = red[0] + red[1] + red[2] + red[3];
  float rn = rsqrtf(tot * (1.0f / (float)kHID) + 1e-6f);
  float4 w4 = *(const float4*)(w + tid * 4);
  uint2 o;
  o.x = f2bf(v0*rn*w4.x) | ((unsigned)f2bf(v1*rn*w4.y) << 16);
  o.y = f2bf(v2*rn*w4.z) | ((unsigned)f2bf(v3*rn*w4.w) << 16);
  *(uint2*)(out + (size_t)row * kHID + tid * 4) = o;
}

// ---------- 256x256 8-phase bf16 MFMA GEMM (r16 VERBATIM) ----------
// OUTMODE: 2=silu(gate)*up pairs->bf16 (N_out=N/2)
//          3=bf16 + k-rope cols [0,512) posOdd   4=bf16 + q-rope [0,1024),
//            k-rope [1024,1536) pos even
template<int OUTMODE>
__global__ __launch_bounds__(512, 2) void gemm8p(
    const unsigned short* __restrict__ A, const unsigned short* __restrict__ B,
    const float* __restrict__ resid, void* __restrict__ Cout,
    const float* __restrict__ ct, const float* __restrict__ st,
    int M, int N, int K) {
  __shared__ unsigned short As[2][2][128][64];   // [buf][half][row][col] 64 KiB
  __shared__ unsigned short Bs[2][2][128][64];   // 64 KiB
  const int tid = threadIdx.x;
  const int lane = tid & 63, wid = tid >> 6;
  const int gx = gridDim.x;
  int id = blockIdx.y * gx + blockIdx.x;
  {
    const int nwg = gx * gridDim.y;           // all grids here are %8 == 0
    const int cpx = nwg >> 3;
    id = (id & 7) * cpx + (id >> 3);          // XCD-contiguous remap
  }
  const int m0 = (id / gx) * 256, n0 = (id % gx) * 256;
  const int wr = wid >> 2, wc = wid & 3;
  const int l15 = lane & 15, lg = lane >> 4;
  const int swz = l15 & 7;
  const int NT = K >> 6;                      // BK=64 tiles (always even here)

  const int scol = ((lane & 7) ^ (lane >> 3)) * 8;
  const unsigned short* Asrc = A + (size_t)(m0 + wid * 16 + (lane >> 3)) * K + scol;
  const unsigned short* Bsrc = B + (size_t)(n0 + wid * 16 + (lane >> 3)) * K + scol;
  const size_t rK8 = (size_t)8 * K, rK128 = (size_t)128 * K;
  const int brow0 = (wc & 1) * 64;            // wave's B rows within half wc>>1

#define STAGEA(t_, h_, b_) do {                                              \
    gload_lds16(Asrc + (size_t)(h_) * rK128 + (size_t)(t_) * 64,             \
                (unsigned short*)&As[b_][h_][0][0] + (wid * 2 + 0) * 512);   \
    gload_lds16(Asrc + (size_t)(h_) * rK128 + rK8 + (size_t)(t_) * 64,       \
                (unsigned short*)&As[b_][h_][0][0] + (wid * 2 + 1) * 512);   \
  } while (0)
#define STAGEB(t_, h_, b_) do {                                              \
    gload_lds16(Bsrc + (size_t)(h_) * rK128 + (size_t)(t_) * 64,             \
                (unsigned short*)&Bs[b_][h_][0][0] + (wid * 2 + 0) * 512);   \
    gload_lds16(Bsrc + (size_t)(h_) * rK128 + rK8 + (size_t)(t_) * 64,       \
                (unsigned short*)&Bs[b_][h_][0][0] + (wid * 2 + 1) * 512);   \
  } while (0)

  bf16x8 afr[2][4], bfr[2][4];   // [kk][mi'] / [kk][nj] — constant-indexed only
#define LOADA(b_, qm_) do {                                                  \
    _Pragma("unroll") for (int kk = 0; kk < 2; ++kk)                         \
    _Pragma("unroll") for (int mi = 0; mi < 4; ++mi)                         \
      afr[kk][mi] = *(const bf16x8*)&As[b_][wr][((qm_) * 4 + mi) * 16 + l15] \
                                       [((kk * 4 + lg) ^ swz) * 8];          \
  } while (0)
#define LOADB(b_, qn_) do {                                                  \
    _Pragma("unroll") for (int kk = 0; kk < 2; ++kk)                         \
    _Pragma("unroll") for (int nj = 0; nj < 2; ++nj)                         \
      bfr[kk][(qn_) * 2 + nj] =                                              \
        *(const bf16x8*)&Bs[b_][wc >> 1][brow0 + ((qn_) * 2 + nj) * 16 + l15]\
                           [((kk * 4 + lg) ^ swz) * 8];                      \
  } while (0)

  f32x4 acc[8][4] = {};
#define MFMAQ(qm_, qn_) do {                                                 \
    __builtin_amdgcn_s_setprio(1);                                           \
    _Pragma("unroll") for (int mi = 0; mi < 4; ++mi)                         \
    _Pragma("unroll") for (int nj = 0; nj < 2; ++nj) {                       \
      acc[(qm_) * 4 + mi][(qn_) * 2 + nj] =                                  \
        __builtin_amdgcn_mfma_f32_16x16x32_bf16(afr[0][mi],                  \
          bfr[0][(qn_) * 2 + nj], acc[(qm_) * 4 + mi][(qn_) * 2 + nj], 0,0,0);\
      acc[(qm_) * 4 + mi][(qn_) * 2 + nj] =                                  \
        __builtin_amdgcn_mfma_f32_16x16x32_bf16(afr[1][mi],                  \
          bfr[1][(qn_) * 2 + nj], acc[(qm_) * 4 + mi][(qn_) * 2 + nj], 0,0,0);\
    }                                                                        \
    __builtin_amdgcn_s_setprio(0);                                           \
  } while (0)

#define BAR_PRE() do {                                                       \
    __builtin_amdgcn_sched_barrier(0);                                       \
    __builtin_amdgcn_s_barrier();                                            \
    asm volatile("s_waitcnt lgkmcnt(0)" ::: "memory");                       \
    __builtin_amdgcn_sched_barrier(0);                                       \
  } while (0)
#define BAR_POST() do {                                                      \
    __builtin_amdgcn_sched_barrier(0);                                       \
    __builtin_amdgcn_s_barrier();                                            \
    __builtin_amdgcn_sched_barrier(0);                                       \
  } while (0)

  // prologue: T0 fully + T1.B; drain T0 (leave T1.B in flight)
  STAGEA(0, 0, 0); STAGEA(0, 1, 0); STAGEB(0, 0, 0); STAGEB(0, 1, 0);
  STAGEB(1, 0, 1); STAGEB(1, 1, 1);
  asm volatile("s_waitcnt vmcnt(4)" ::: "memory");
  __builtin_amdgcn_sched_barrier(0);
  __builtin_amdgcn_s_barrier();
  __builtin_amdgcn_sched_barrier(0);

  for (int t0 = 0; t0 < NT; t0 += 2) {
    const bool more = (t0 + 2 < NT);   // next tile-pair exists (t0+2 and t0+3)
    // ---- tile t0 (buf 0) ----
    LOADA(0, 0); LOADB(0, 0);                 // ph1: A-lo + B01
    STAGEA(t0 + 1, 0, 1);
    BAR_PRE(); MFMAQ(0, 0); BAR_POST();
    LOADB(0, 1);                              // ph2: B23
    STAGEA(t0 + 1, 1, 1);
    BAR_PRE(); MFMAQ(0, 1); BAR_POST();
    LOADA(0, 1);                              // ph3: A-hi
    if (more) STAGEB(t0 + 2, 0, 0);
    BAR_PRE(); MFMAQ(1, 0); BAR_POST();
    if (more) STAGEB(t0 + 2, 1, 0);           // ph4 (late vmcnt)
    BAR_PRE(); MFMAQ(1, 1);
    __builtin_amdgcn_sched_barrier(0);
    if (more) asm volatile("s_waitcnt vmcnt(4)" ::: "memory");
    else      asm volatile("s_waitcnt vmcnt(0)" ::: "memory");
    BAR_POST();
    // ---- tile t0+1 (buf 1) ----
    LOADA(1, 0); LOADB(1, 0);                 // ph5
    if (more) STAGEA(t0 + 2, 0, 0);
    BAR_PRE(); MFMAQ(0, 0); BAR_POST();
    LOADB(1, 1);                              // ph6
    if (more) STAGEA(t0 + 2, 1, 0);
    BAR_PRE(); MFMAQ(0, 1); BAR_POST();
    LOADA(1, 1);                              // ph7
    if (more) STAGEB(t0 + 3, 0, 1);
    BAR_PRE(); MFMAQ(1, 0); BAR_POST();
    if (more) STAGEB(t0 + 3, 1, 1);           // ph8 (late vmcnt)
    BAR_PRE(); MFMAQ(1, 1);
    __builtin_amdgcn_sched_barrier(0);
    if (more) asm volatile("s_waitcnt vmcnt(4)" ::: "memory");
    BAR_POST();
  }
#undef STAGEA
#undef STAGEB
#undef LOADA
#undef LOADB
#undef MFMAQ
#undef BAR_PRE
#undef BAR_POST

  // ---------- epilogue ----------
  const int r0 = lg * 4;
  const int bc = n0 + wc * 64;
  #pragma unroll
  for (int mi = 0; mi < 8; ++mi) {
    #pragma unroll
    for (int r = 0; r < 4; ++r) {
      const size_t grow = (size_t)(m0 + wr * 128 + mi * 16 + r0 + r);
      if (OUTMODE == 2) {
        #pragma unroll
        for (int p = 0; p < 2; ++p) {
          float gv = acc[mi][2 * p][r], uv = acc[mi][2 * p + 1][r];
          float res = gv / (1.f + __expf(-gv)) * uv;
          ((unsigned short*)Cout)[grow * (size_t)(N >> 1) + (bc >> 1) + p * 16 + l15] = f2bf(res);
        }
      } else {
        bool doR = false; int pos = 0;
        if (OUTMODE == 3) { doR = bc < 512; pos = 2 * ((int)grow & 7) + 1; }
        if (OUTMODE == 4) {
          if (bc < 1024)      { doR = true; pos = (int)grow & 7; }
          else if (bc < 1536) { doR = true; pos = 2 * ((int)grow & 7); }
        }
        unsigned short* o16 = (unsigned short*)Cout;
        if (doR) {
          #pragma unroll
          for (int nj = 0; nj < 2; ++nj) {
            float a = acc[mi][nj][r], b = acc[mi][nj + 2][r];
            float c = ct[pos * 32 + nj * 16 + l15];
            float s = st[pos * 32 + nj * 16 + l15];
            o16[grow * N + bc + nj * 16 + l15]       = f2bf(a * c - b * s);
            o16[grow * N + bc + (nj + 2) * 16 + l15] = f2bf(b * c + a * s);
          }
        } else {
          #pragma unroll
          for (int nj = 0; nj < 4; ++nj)
            o16[grow * N + bc + nj * 16 + l15] = f2bf(acc[mi][nj][r]);
        }
      }
    }
  }
}

// ---------- TMx128 bf16 MFMA GEMM, BK=32, 3-buffer LDS (r16 VERBATIM) ----------
// OUTMODE: 5 = bf16 out + f32 resid (Wo -> hbuf16)
//          6 = f32 out + bf16 resid (Down -> d_out, resid=hbuf16)
template<int OUTMODE, int TM>
__global__ __launch_bounds__(512, 4) void gemmk(
    const unsigned short* __restrict__ A, const unsigned short* __restrict__ B,
    const void* __restrict__ residv, void* __restrict__ Cout,
    const float* __restrict__ ct, const float* __restrict__ st,
    int M, int N, int K) {
  constexpr int ABUFE = TM * 32;            // elems per A buffer
  constexpr int BBUFE = 128 * 32;
  constexpr int WRS   = TM / 4;             // wave row span: 64 or 32
  constexpr int MI    = WRS / 16;           // 4 or 2
  constexpr int LPS   = (TM == 256) ? 3 : 2; // gloads per stage per wave
  __shared__ unsigned short As[3 * ABUFE];
  __shared__ unsigned short Bs[3 * BBUFE];
  const int tid = threadIdx.x;
  const int lane = tid & 63, wid = tid >> 6;
  const int gx = gridDim.x;
  int id = blockIdx.y * gx + blockIdx.x;
  {
    const int nwg = gx * gridDim.y;         // all grids here are %8 == 0
    const int cpx = nwg >> 3;
    id = (id & 7) * cpx + (id >> 3);        // XCD-contiguous remap
  }
  const int m0 = (id / gx) * TM, n0 = (id % gx) * 128;
  const int wr = wid >> 1, wc = wid & 1;
  const int l15 = lane & 15, lg = lane >> 4;
  const int NT = K >> 5;

  const int sr4 = lane >> 2, sc = lane & 3;
  const int arow0 = (TM == 256) ? (wid * 32 + sr4) : (wid * 16 + sr4);
  const int brow0 = wid * 16 + sr4;
  const unsigned short* Asrc = A + (size_t)(m0 + arow0) * K + (sc ^ ((arow0 >> 1) & 3)) * 8;
  const unsigned short* Bsrc = B + (size_t)(n0 + brow0) * K + (sc ^ ((brow0 >> 1) & 3)) * 8;
  const size_t rK16 = (size_t)16 * K;

#define STAGE(t_, b_) do {                                                   \
    const size_t _k0 = (size_t)(t_) * 32;                                    \
    if (TM == 256) {                                                         \
      gload_lds16(Asrc + _k0,        As + (b_) * ABUFE + wid * 1024);        \
      gload_lds16(Asrc + rK16 + _k0, As + (b_) * ABUFE + wid * 1024 + 512);  \
    } else {                                                                 \
      gload_lds16(Asrc + _k0,        As + (b_) * ABUFE + wid * 512);         \
    }                                                                        \
    gload_lds16(Bsrc + _k0,          Bs + (b_) * BBUFE + wid * 512);         \
  } while (0)

  f32x4 acc[MI][4] = {};
  STAGE(0, 0); STAGE(1, 1);

  const int rck = (lg ^ ((l15 >> 1) & 3)) * 8;   // read-side swizzle chunk
  int cur = 0, nx2 = 2;
  for (int t = 0; t < NT; ++t) {
    __builtin_amdgcn_sched_barrier(0);
    if (t + 1 < NT) asm volatile("s_waitcnt vmcnt(%0)" :: "i"(LPS) : "memory");
    else            asm volatile("s_waitcnt vmcnt(0)" ::: "memory");
    __builtin_amdgcn_s_barrier();
    __builtin_amdgcn_sched_barrier(0);
    if (t + 2 < NT) STAGE(t + 2, nx2);

    const unsigned short* Ab = As + cur * ABUFE + (wr * WRS + l15) * 32 + rck;
    const unsigned short* Bb = Bs + cur * BBUFE + (wc * 64 + l15) * 32 + rck;
    bf16x8 af[MI], bf[4];
    #pragma unroll
    for (int mi = 0; mi < MI; ++mi) af[mi] = *(const bf16x8*)(Ab + mi * 512);
    #pragma unroll
    for (int nj = 0; nj < 4; ++nj) bf[nj] = *(const bf16x8*)(Bb + nj * 512);
    __builtin_amdgcn_s_setprio(1);
    #pragma unroll
    for (int mi = 0; mi < MI; ++mi)
      #pragma unroll
      for (int nj = 0; nj < 4; ++nj)
        acc[mi][nj] = __builtin_amdgcn_mfma_f32_16x16x32_bf16(af[mi], bf[nj], acc[mi][nj], 0, 0, 0);
    __builtin_amdgcn_s_setprio(0);
    cur = (cur == 2) ? 0 : cur + 1;
    nx2 = (nx2 == 2) ? 0 : nx2 + 1;
  }
#undef STAGE

  const int r0 = lg * 4;
  const int bc = n0 + wc * 64;
  #pragma unroll
  for (int mi = 0; mi < MI; ++mi) {
    #pragma unroll
    for (int r = 0; r < 4; ++r) {
      const size_t grow = (size_t)(m0 + wr * WRS + mi * 16 + r0 + r);
      #pragma unroll
      for (int nj = 0; nj < 4; ++nj) {
        const size_t gi = grow * N + (bc + nj * 16 + l15);
        float v = acc[mi][nj][r];
        if (OUTMODE == 5) {
          v += ((const float*)residv)[gi];
          ((unsigned short*)Cout)[gi] = f2bf(v);
        } else {  // OUTMODE 6
          v += bf2f(((const unsigned short*)residv)[gi]);
          ((float*)Cout)[gi] = v;
        }
      }
    }
  }
}

// ---------- CSR build ----------
__global__ void csr_count_kernel(const int* __restrict__ dst, int* __restrict__ cnt) {
  int e = blockIdx.x * 256 + threadIdx.x;
  if (e < kE) atomicAdd(&cnt[dst[e]], 1);
}
__global__ __launch_bounds__(1024) void csr_scan_kernel(
    const int* __restrict__ cnt, int* __restrict__ start) {
  __shared__ int tmp[1024];
  int t = threadIdx.x;
  tmp[t] = cnt[t];
  __syncthreads();
  for (int off = 1; off < 1024; off <<= 1) {
    int add = (t >= off) ? tmp[t - off] : 0;
    __syncthreads();
    tmp[t] += add;
    __syncthreads();
  }
  start[t + 1] = tmp[t];
  if (t == 0) start[0] = 0;
}
__global__ void csr_scatter_kernel(const int* __restrict__ dst, const int* __restrict__ start,
                                   int* __restrict__ cursor, int* __restrict__ elist) {
  int e = blockIdx.x * 256 + threadIdx.x;
  if (e < kE) {
    int d = dst[e];
    int pos = atomicAdd(&cursor[d], 1);
    elist[start[d] + pos] = e;
  }
}

// ---------- MFMA graph attention: one wave per (node, kv-head) (r16 VERBATIM) ----------
__global__ __launch_bounds__(256) void attn_mfma_kernel(
    const unsigned short* __restrict__ qkv,  // roped
    const unsigned short* __restrict__ ekv,  // ek roped
    const int* __restrict__ srcIdx, const int* __restrict__ elist,
    const int* __restrict__ start,
    unsigned short* __restrict__ aggb) {
  const int n = blockIdx.x >> 1;
  const int g = (blockIdx.x & 1) * 4 + (threadIdx.x >> 6);
  const int lane = threadIdx.x & 63;
  const int l15 = lane & 15, lg = lane >> 4;

  const int h = g * 2 + (l15 >> 3), q = l15 & 7;
  const unsigned short* qrow = qkv + ((size_t)n * 8 + q) * 2048 + h * 64 + lg * 8;
  const bf16x8 qf0 = *(const bf16x8*)qrow;
  const bf16x8 qf1 = *(const bf16x8*)(qrow + 32);

  float m = -3.4e38f, sh = 0.f;
  f32x4 oacc[4];
  #pragma unroll
  for (int t = 0; t < 4; ++t) oacc[t] = (f32x4){0.f, 0.f, 0.f, 0.f};

  const int kparity = l15 & 1;
  const int t_ = l15 >> 1;
  const int lgh = lg & 1;
  const int eS = lg >> 1;

  const int s0 = start[n], s1 = start[n + 1];
  for (int jj = s0; jj < s1; jj += 2) {
    const int e0 = elist[jj];
    const bool has1 = (jj + 1 < s1);
    const int e1 = has1 ? elist[jj + 1] : e0;
    const int sn0 = srcIdx[e0], sn1 = srcIdx[e1];

    const unsigned short* kr0 = kparity
        ? ekv + ((size_t)e0 * 8 + t_) * 1024 + g * 64 + lg * 8
        : qkv + ((size_t)sn0 * 8 + t_) * 2048 + 1024 + g * 64 + lg * 8;
    const unsigned short* kr1 = kparity
        ? ekv + ((size_t)e1 * 8 + t_) * 1024 + g * 64 + lg * 8
        : qkv + ((size_t)sn1 * 8 + t_) * 2048 + 1024 + g * 64 + lg * 8;
    bf16x8 ka0 = *(const bf16x8*)kr0, ka1 = *(const bf16x8*)(kr0 + 32);
    bf16x8 kc0 = *(const bf16x8*)kr1, kc1 = *(const bf16x8*)(kr1 + 32);

    const int evsel = eS ? e1 : e0;
    const int snsel = eS ? sn1 : sn0;
    const unsigned short* vn = qkv + ((size_t)snsel * 8 + lgh * 4) * 2048 + 1536 + g * 64;
    const unsigned short* ve = ekv + ((size_t)evsel * 8 + lgh * 4) * 1024 + 512 + g * 64;

    f32x4 z = (f32x4){0.f, 0.f, 0.f, 0.f};
    f32x4 sa = __builtin_amdgcn_mfma_f32_16x16x32_bf16(ka0, qf0, z, 0, 0, 0);
    sa       = __builtin_amdgcn_mfma_f32_16x16x32_bf16(ka1, qf1, sa, 0, 0, 0);
    f32x4 sb = __builtin_amdgcn_mfma_f32_16x16x32_bf16(kc0, qf0, z, 0, 0, 0);
    sb       = __builtin_amdgcn_mfma_f32_16x16x32_bf16(kc1, qf1, sb, 0, 0, 0);

    float l0[4], l1[4];
    float lmax = -3.4e38f;
    #pragma unroll
    for (int r = 0; r < 4; ++r) {
      l0[r] = sa[r] * 0.125f;
      l1[r] = has1 ? sb[r] * 0.125f : -3.4e38f;
      lmax = fmaxf(lmax, fmaxf(l0[r], l1[r]));
    }
    lmax = fmaxf(lmax, __shfl_xor(lmax, 16));
    lmax = fmaxf(lmax, __shfl_xor(lmax, 32));
    const float mnew = fmaxf(m, lmax);
    const float scale = __expf(m - mnew);
    float p0[4], p1[4], ps = 0.f;
    #pragma unroll
    for (int r = 0; r < 4; ++r) {
      p0[r] = __expf(l0[r] - mnew);
      p1[r] = __expf(l1[r] - mnew);
      ps += p0[r] + p1[r];
    }
    ps += __shfl_xor(ps, 16);
    ps += __shfl_xor(ps, 32);
    sh = sh * scale + ps;
    m = mnew;

    #pragma unroll
    for (int r = 0; r < 4; ++r) {
      float sr = __shfl(scale, lg * 4 + r);
      #pragma unroll
      for (int t = 0; t < 4; ++t) oacc[t][r] *= sr;
    }

    unsigned w00 = pkbf(p0[0], p0[1]), w01 = pkbf(p0[2], p0[3]);
    unsigned w10 = pkbf(p1[0], p1[1]), w11 = pkbf(p1[2], p1[3]);
    const int L1 = l15 + 32 * lgh, L2 = L1 + 16;
    unsigned a0 = __shfl(w00, L1), a1 = __shfl(w01, L1);
    unsigned a2 = __shfl(w00, L2), a3 = __shfl(w01, L2);
    unsigned b0 = __shfl(w10, L1), b1 = __shfl(w11, L1);
    unsigned b2 = __shfl(w10, L2), b3 = __shfl(w11, L2);
    uint4 wv;
    wv.x = eS ? b0 : a0; wv.y = eS ? b1 : a1;
    wv.z = eS ? b2 : a2; wv.w = eS ? b3 : a3;
    const bf16x8 pf = __builtin_bit_cast(bf16x8, wv);

    #pragma unroll
    for (int t = 0; t < 4; ++t) {
      const int col = t * 16 + l15;
      ushort8 vr;
      #pragma unroll
      for (int j = 0; j < 8; ++j)
        vr[j] = (j & 1) ? ve[(j >> 1) * 1024 + col] : vn[(j >> 1) * 2048 + col];
      const bf16x8 vf = __builtin_bit_cast(bf16x8, vr);
      oacc[t] = __builtin_amdgcn_mfma_f32_16x16x32_bf16(pf, vf, oacc[t], 0, 0, 0);
    }
  }

  #pragma unroll
  for (int r = 0; r < 4; ++r) {
    const float sr = __shfl(sh, lg * 4 + r);
    const float inv = 1.f / (sr + 1e-16f);
    const int hq = lg * 4 + r;
    const int hh = g * 2 + (hq >> 3), qq = hq & 7;
    unsigned short* op = aggb + ((size_t)n * 8 + qq) * 1024 + hh * 64 + l15;
    #pragma unroll
    for (int t = 0; t < 4; ++t) op[t * 16] = f2bf(oacc[t][r] * inv);
  }
}

extern "C" void kernel_launch(void* const* d_in, const int* in_sizes, int n_in,
                              void* d_out, int out_size, void* d_ws, size_t ws_size,
                              hipStream_t stream) {
  const float* hidden = (const float*)d_in[0];
  const int*   eidx   = (const int*)d_in[1];
  const float* ehid   = (const float*)d_in[2];
  const float* Wq     = (const float*)d_in[3];
  const float* Wk     = (const float*)d_in[4];
  const float* Wv     = (const float*)d_in[5];
  const float* Wo     = (const float*)d_in[6];
  const float* Wgate  = (const float*)d_in[7];
  const float* Wup    = (const float*)d_in[8];
  const float* Wdown  = (const float*)d_in[9];
  const float* ln1    = (const float*)d_in[10];
  const float* ln2    = (const float*)d_in[11];
  const int* srcIdx = eidx;
  const int* dstIdx = eidx + kE;

  char* wsb = (char*)d_ws;
  size_t off = 0;
  auto alloc = [&](size_t bytes) { char* p = wsb + off; off += (bytes + 255) & ~(size_t)255; return p; };
  unsigned short* eh16   = (unsigned short*)alloc(134217728);  // [65536][1024]
  unsigned short* ekv16  = (unsigned short*)alloc(134217728);  // [65536][1024] ek|ev; reused as gm16 [8192][4096]
  unsigned short* qkv16  = (unsigned short*)alloc(33554432);   // [8192][2048] q|k|v
  unsigned short* x16    = (unsigned short*)alloc(16777216);   // [8192][1024]; reused as h216
  unsigned short* agg16  = (unsigned short*)alloc(16777216);   // [8192][1024]
  unsigned short* hbuf16 = (unsigned short*)alloc(16777216);   // [8192][1024] bf16 (h)
  unsigned short* wqkv16 = (unsigned short*)alloc(4194304);    // [2048][1024] = Wq|Wk|Wv
  unsigned short* wo16   = (unsigned short*)alloc(2097152);    // [1024][1024]
  unsigned short* wgu16  = (unsigned short*)alloc(16777216);   // [8192][1024] interleaved gate/up
  unsigned short* wd16   = (unsigned short*)alloc(8388608);    // [1024][4096]
  int* cnt    = (int*)alloc(4096);
  int* cursor = (int*)alloc(4096);   // adjacent to cnt -> one memset
  int* startb = (int*)alloc(4352);   // 1025 ints
  int* elist  = (int*)alloc(32768);
  float* ct   = (float*)alloc(2048);
  float* st   = (float*)alloc(2048);
  unsigned short* gm16 = ekv16;   // silu output (ekv dead after attention)
  unsigned short* h216 = x16;     // rmsnorm2 out (x16 dead after QKV GEMM)
  float* outp = (float*)d_out;

  hipMemsetAsync(cnt, 0, 8192, stream);     // cnt + cursor

  // merged pre-GEMM prep: rmsnorm1 + all conversions + rope tables (1 launch)
  prep_kernel<<<48641, 256, 0, stream>>>(hidden, ln1, ehid,
                                         Wq, Wk, Wv, Wo, Wgate, Wup, Wdown,
                                         x16, eh16, wqkv16, wo16, wgu16, wd16,
                                         ct, st);

  // CSR build
  csr_count_kernel<<<32, 256, 0, stream>>>(dstIdx, cnt);
  csr_scan_kernel<<<1, 1024, 0, stream>>>(cnt, startb);
  csr_scatter_kernel<<<32, 256, 0, stream>>>(dstIdx, startb, cursor, elist);

  // fused projections (rope fused in epilogues) — 8-phase for the big GEMMs
  gemm8p<4><<<dim3(8, 32),  512, 0, stream>>>(x16,  wqkv16, nullptr, qkv16, ct, st, 8192, 2048, 1024);
  gemm8p<3><<<dim3(4, 256), 512, 0, stream>>>(eh16, wqkv16 + 1024 * 1024, nullptr, ekv16, ct, st, 65536, 1024, 1024);

  // fused MFMA graph attention
  attn_mfma_kernel<<<2048, 256, 0, stream>>>(qkv16, ekv16, srcIdx, elist, startb, agg16);

  // h = hidden + agg @ Wo^T  -> bf16 hbuf
  gemmk<5, 128><<<dim3(8, 64), 512, 0, stream>>>(agg16, wo16, hidden, hbuf16, ct, st, 8192, 1024, 1024);

  // MLP (silu fused in GateUp epilogue via interleaved weights)
  rmsnorm_b16in_kernel<<<kN * kQL, 256, 0, stream>>>(hbuf16, ln2, h216);
  gemm8p<2><<<dim3(32, 32), 512, 0, stream>>>(h216, wgu16, nullptr, gm16, ct, st, 8192, 8192, 1024);
  gemmk<6, 128><<<dim3(8, 64), 512, 0, stream>>>(gm16, wd16, hbuf16, outp, ct, st, 8192, 1024, 4096);
}